// Round 20
// baseline (152.033 us; speedup 1.0000x reference)
//
#include <hip/hip_runtime.h>
#include <math.h>

#define NN 65536
#define HH 128
#define DHH 16
#define NE 1048576
#define HID 256
#define LNEPS 1e-5f
#define NB 256      // buckets for CSR build
#define BCAP 6144   // max edges per bucket (mean 4096, sd 64 -> +32 sd)

typedef __attribute__((ext_vector_type(8))) short bf16x8;
typedef __attribute__((ext_vector_type(8))) unsigned short u16x8;
typedef __attribute__((ext_vector_type(4))) float f32x4;
typedef __attribute__((ext_vector_type(2))) float f32x2;

static __device__ __forceinline__ unsigned short f2bf(float f) {
    union { float f; unsigned u; } c; c.f = f;
    unsigned r = c.u + 0x7fffu + ((c.u >> 16) & 1u);
    return (unsigned short)(r >> 16);
}
static __device__ __forceinline__ float bf2f(unsigned short u) {
    union { unsigned u; float f; } c; c.u = ((unsigned)u) << 16;
    return c.f;
}
// gelu_tanh(x) == x*sigmoid(2c(x+0.044715x^3))  [exact identity]
static __device__ __forceinline__ float gelu_tanh(float x) {
    const float a = -2.302225282f;  // -2*log2(e)*0.7978845608
    const float u = a * (x + 0.044715f * x * x * x);
    const float e = __builtin_amdgcn_exp2f(u);
    return x * __builtin_amdgcn_rcpf(1.f + e);
}

// ---------------- K1: LN1+QKV w/ inline fp32->bf16 panel staging (0..511) ∥ edge bin (512..767) --
__global__ __launch_bounds__(256) void k_qkv_bin(
    const float* __restrict__ x, const float* __restrict__ g, const float* __restrict__ bl,
    const float* __restrict__ wq, const float* __restrict__ wk, const float* __restrict__ wv,
    const float* __restrict__ bq, const float* __restrict__ bk, const float* __restrict__ bv,
    unsigned short* __restrict__ qo, unsigned char* __restrict__ kv8,
    const int* __restrict__ er, const int* __restrict__ ec,
    int* __restrict__ gcur, unsigned long long* __restrict__ pairs) {
    __shared__ int smem4[16384];  // 64 KB arena
    const int t = threadIdx.x;
    if (blockIdx.x < 512) {
        unsigned short* aT = (unsigned short*)smem4;            // 32 KB
        unsigned short* wbuf = (unsigned short*)smem4 + 16384;  // 32 KB
        const int rb = blockIdx.x * 128;
        const int w = t >> 6, l = t & 63;
        {
            const int sr0 = w * 32 + (l >> 2), qd = l & 3;
#pragma unroll 1
            for (int rr = 0; rr < 2; rr++) {
                const int row = sr0 + rr * 16;
                const float4* xr = reinterpret_cast<const float4*>(x + (size_t)(rb + row) * HH) + qd * 8;
                float xa[32]; float s = 0.f, ss = 0.f;
#pragma unroll
                for (int i = 0; i < 8; i++) {
                    float4 v4 = xr[i];
                    xa[i * 4 + 0] = v4.x; xa[i * 4 + 1] = v4.y; xa[i * 4 + 2] = v4.z; xa[i * 4 + 3] = v4.w;
                    s += v4.x + v4.y + v4.z + v4.w;
                    ss += v4.x * v4.x + v4.y * v4.y + v4.z * v4.z + v4.w * v4.w;
                }
                s += __shfl_xor(s, 1); s += __shfl_xor(s, 2);
                ss += __shfl_xor(ss, 1); ss += __shfl_xor(ss, 2);
                const float mu = s * (1.f / HH);
                const float rs = rsqrtf(ss * (1.f / HH) - mu * mu + LNEPS);
#pragma unroll
                for (int c = 0; c < 4; c++) {
                    u16x8 w8;
#pragma unroll
                    for (int j2 = 0; j2 < 8; j2++) {
                        const int d = qd * 32 + c * 8 + j2;
                        w8[j2] = f2bf((xa[c * 8 + j2] - mu) * rs * g[d] + bl[d]);
                    }
                    const int uoff = (row * 128 + qd * 32 + c * 8) ^ ((row & 7) << 3);
                    *reinterpret_cast<u16x8*>(&aT[uoff]) = w8;
                }
            }
            // stage wq panel, converting fp32 -> packed bf16 inline
#pragma unroll
            for (int i = 0; i < 8; i++) {
                const int off = i * 2048 + t * 8;
                const int k8 = off >> 10, n = (off >> 3) & 127;
                u16x8 w8;
#pragma unroll
                for (int j = 0; j < 8; j++) w8[j] = f2bf(wq[(size_t)(k8 * 8 + j) * 128 + n]);
                *reinterpret_cast<u16x8*>(&wbuf[off]) = w8;
            }
        }
        __syncthreads();
        const int lr = l & 15, lg = l >> 4;
        const int row0 = w * 32 + lr;
        const int row1 = w * 32 + 16 + lr;
        bf16x8 a0[4], a1[4];
#pragma unroll
        for (int kc = 0; kc < 4; kc++) {
            a0[kc] = *reinterpret_cast<const bf16x8*>(&aT[(row0 * 128 + kc * 32 + lg * 8) ^ ((row0 & 7) << 3)]);
            a1[kc] = *reinterpret_cast<const bf16x8*>(&aT[(row1 * 128 + kc * 32 + lg * 8) ^ ((row1 & 7) << 3)]);
        }
#pragma unroll 1
        for (int m = 0; m < 3; m++) {
            const float* Bb = (m == 0) ? bq : (m == 1) ? bk : bv;
            f32x4 ac0[8], ac1[8];
#pragma unroll
            for (int g8 = 0; g8 < 8; g8++) { ac0[g8] = (f32x4){0.f,0.f,0.f,0.f}; ac1[g8] = (f32x4){0.f,0.f,0.f,0.f}; }
#pragma unroll
            for (int g8 = 0; g8 < 8; g8++)
#pragma unroll
                for (int kc = 0; kc < 4; kc++) {
                    const bf16x8 bfr = *reinterpret_cast<const bf16x8*>(&wbuf[(((kc << 2) + lg) * 128 + g8 * 16 + lr) << 3]);
                    ac0[g8] = __builtin_amdgcn_mfma_f32_16x16x32_bf16(a0[kc], bfr, ac0[g8], 0, 0, 0);
                    ac1[g8] = __builtin_amdgcn_mfma_f32_16x16x32_bf16(a1[kc], bfr, ac1[g8], 0, 0, 0);
                }
            __syncthreads();
            if (m < 2) {
                const float* nsrcf = (m == 0) ? wk : wv;
#pragma unroll
                for (int i = 0; i < 8; i++) {
                    const int off = i * 2048 + t * 8;
                    const int k8 = off >> 10, n = (off >> 3) & 127;
                    u16x8 w8;
#pragma unroll
                    for (int j = 0; j < 8; j++) w8[j] = f2bf(nsrcf[(size_t)(k8 * 8 + j) * 128 + n]);
                    *reinterpret_cast<u16x8*>(&wbuf[off]) = w8;
                }
            }
#pragma unroll
            for (int g8 = 0; g8 < 8; g8++) {
                const float bias = Bb[g8 * 16 + lr];
#pragma unroll
                for (int j = 0; j < 4; j++) {
                    const int ra = rb + w * 32 + 4 * lg + j;
                    const int rbb = ra + 16;
                    const float y0 = ac0[g8][j] + bias, y1 = ac1[g8][j] + bias;
                    if (m == 0) {
                        qo[(size_t)ra * HH + g8 * 16 + lr] = f2bf(y0);
                        qo[(size_t)rbb * HH + g8 * 16 + lr] = f2bf(y1);
                    } else {
                        const int off = g8 * 32 + lr + ((m == 2) ? 16 : 0);
                        const int pk0 = __builtin_amdgcn_cvt_pk_fp8_f32(y0, y0, 0, false);
                        const int pk1 = __builtin_amdgcn_cvt_pk_fp8_f32(y1, y1, 0, false);
                        kv8[(size_t)ra * 256 + off] = (unsigned char)(pk0 & 0xff);
                        kv8[(size_t)rbb * 256 + off] = (unsigned char)(pk1 & 0xff);
                    }
                }
            }
            if (m < 2) __syncthreads();
        }
    } else {
        int* cnt = smem4;
        int* cur = smem4 + 256;
        int* base = smem4 + 512;
        const int e0 = (blockIdx.x - 512) * 4096;
        cnt[t] = 0;
        __syncthreads();
        int rows[16], cols[16];
#pragma unroll
        for (int i = 0; i < 16; i++) {
            const int e = e0 + i * 256 + t;
            rows[i] = er[e];
            cols[i] = ec[e];
            atomicAdd(&cnt[rows[i] >> 8], 1);
        }
        __syncthreads();
        if (cnt[t] > 0) base[t] = atomicAdd(&gcur[t], cnt[t]);
        cur[t] = 0;
        __syncthreads();
#pragma unroll
        for (int i = 0; i < 16; i++) {
            const int b = rows[i] >> 8;
            const int slot = atomicAdd(&cur[b], 1);
            pairs[(size_t)b * BCAP + base[b] + slot] =
                ((unsigned long long)rows[i] << 32) | (unsigned)cols[i];
        }
    }
}

// ---------------- K2: CSR finalize + degree sort (0..255) ∥ pack wo/w1/w2 (256..575) ------------
__global__ __launch_bounds__(256) void k_csr_pack(
    const unsigned long long* __restrict__ pairs, const int* __restrict__ gcur,
    int* __restrict__ offs, int* __restrict__ csr_col, int* __restrict__ permg,
    const float* __restrict__ wo, const float* __restrict__ w1, const float* __restrict__ w2,
    unsigned short* __restrict__ wpack) {
    __shared__ int smem4[7168];
    const int t = threadIdx.x;
    if (blockIdx.x < 256) {
        int* cnt = smem4;
        int* sc = smem4 + 256;
        int* cur = smem4 + 512;
        int* colbuf = smem4 + 768;          // BCAP ints
        int* hist = smem4 + 7040;           // 64
        int* hbase = smem4 + 7104;          // 64
        const int b = blockIdx.x;
        sc[t] = gcur[t];
        __syncthreads();
        for (int d = 1; d < NB; d <<= 1) {
            int vv = (t >= d) ? sc[t - d] : 0;
            __syncthreads();
            sc[t] += vv;
            __syncthreads();
        }
        const int cbase = (b == 0) ? 0 : sc[b - 1];
        const int tot = gcur[b];
        __syncthreads();
        const unsigned long long* bp = pairs + (size_t)b * BCAP;
        cnt[t] = 0;
        __syncthreads();
        for (int i = t; i < tot; i += 256) {
            const unsigned long long u = bp[i];
            atomicAdd(&cnt[(int)(u >> 32) & 255], 1);
        }
        __syncthreads();
        sc[t] = cnt[t];
        __syncthreads();
        for (int d = 1; d < 256; d <<= 1) {
            int vv = (t >= d) ? sc[t - d] : 0;
            __syncthreads();
            sc[t] += vv;
            __syncthreads();
        }
        const int excl = sc[t] - cnt[t];
        offs[b * 256 + t] = cbase + excl;
        cur[t] = excl;
        if (b == NB - 1 && t == 255) offs[NN] = NE;
        __syncthreads();
        for (int i = t; i < tot; i += 256) {
            const unsigned long long u = bp[i];
            const int r = (int)(u >> 32) & 255;
            const int p = atomicAdd(&cur[r], 1);
            colbuf[p] = (int)(unsigned)u;
        }
        __syncthreads();
        for (int i = t; i < tot; i += 256) csr_col[cbase + i] = colbuf[i];

        // ---- per-bucket degree counting-sort -> permutation ----
        if (t < 64) hist[t] = 0;
        __syncthreads();
        const int deg = min(cnt[t], 63);
        atomicAdd(&hist[deg], 1);
        __syncthreads();
        if (t == 0) {
            int runb = 0;
            for (int i2 = 0; i2 < 64; i2++) { hbase[i2] = runb; runb += hist[i2]; }
        }
        __syncthreads();
        if (t < 64) hist[t] = 0;
        __syncthreads();
        const int rk = hbase[deg] + atomicAdd(&hist[deg], 1);
        permg[b * 256 + rk] = b * 256 + t;
    } else {
        const int b2 = blockIdx.x - 256;
        const float* src; unsigned short* dst; int N, idx;
        if (b2 < 64)       { src = wo; dst = wpack;          N = 128; idx = b2 * 256 + t; }
        else if (b2 < 192) { src = w1; dst = wpack + 16384;  N = 256; idx = (b2 - 64) * 256 + t; }
        else               { src = w2; dst = wpack + 49152;  N = 128; idx = (b2 - 192) * 256 + t; }
        const int k = idx / N, n = idx % N;
        dst[(((k >> 3) * N + n) << 3) + (k & 7)] = f2bf(src[idx]);
    }
}

// ---------------- K3: fused attention (8-edge-wide pipeline) + wo + res + LN2 + MLP -------------
__global__ __launch_bounds__(256, 2) void k_at(
    const unsigned short* __restrict__ q, const unsigned char* __restrict__ kv,
    const int* __restrict__ offs, const int* __restrict__ csr_col,
    const int* __restrict__ perm,
    const unsigned short* __restrict__ wop, const float* __restrict__ bo,
    const float* __restrict__ x, const float* __restrict__ g2, const float* __restrict__ bl2,
    const unsigned short* __restrict__ w1p, const float* __restrict__ b1,
    const unsigned short* __restrict__ w2p, const float* __restrict__ b2,
    float* __restrict__ out) {
    __shared__ unsigned short aT[64 * 128];   // 16 KB: agg tile, then hn tile
    __shared__ unsigned short tT[64 * 256];   // 32 KB
    __shared__ unsigned short wbuf[16384];    // 32 KB
    const int t = threadIdx.x;
    const int rb = blockIdx.x * 64;
    const int w = t >> 6, l = t & 63;
    const int m0 = w * 16, lr = l & 15, lg = l >> 4;
    const int row = m0 + lr;

    // stage wo panel up-front (direct)
#pragma unroll
    for (int i = 0; i < 8; i++) {
        const int off = i * 2048 + t * 8;
        *reinterpret_cast<u16x8*>(&wbuf[off]) = *reinterpret_cast<const u16x8*>(wop + off);
    }

    // ---- attention: 2 (row,head) units per thread, 8-edge-wide pipeline -> aT (swizzled bf16) --
#pragma unroll 1
    for (int u = 0; u < 2; u++) {
        const int rl = (t >> 3) + u * 32;        // local row 0..63
        const int arow = perm[rb + rl];          // degree-sorted global row
        const int h = t & 7;
        const int c0 = offs[arow];
        const int cnt = offs[arow + 1] - c0;
        int mx = cnt;
#pragma unroll
        for (int d = 8; d < 64; d <<= 1) mx = max(mx, __shfl_xor(mx, d));
        mx = (mx + 7) & ~7;

        float qf[16];
        {
            const u16x8* qp = reinterpret_cast<const u16x8*>(q + (size_t)arow * HH + h * DHH);
            u16x8 q0 = qp[0], q1 = qp[1];
#pragma unroll
            for (int j = 0; j < 8; j++) { qf[j] = bf2f(q0[j]); qf[8 + j] = bf2f(q1[j]); }
        }
        float m = 0.f, den = 0.f;
        float acc[16] = {};

        // prologue: kv for edges 0..7 in flight; cols for edges 8..15 buffered
        int ncols[8];
        int4 kd[8], vd[8];
#pragma unroll
        for (int j = 0; j < 8; j++) {
            const int cj = (j < cnt) ? csr_col[c0 + j] : 0;
            const int4* p = reinterpret_cast<const int4*>(kv + (size_t)cj * 256 + h * 32);
            kd[j] = p[0]; vd[j] = p[1];
        }
#pragma unroll
        for (int j = 0; j < 8; j++) ncols[j] = (8 + j < cnt) ? csr_col[c0 + 8 + j] : 0;

        for (int e = 0; e < mx; e += 8) {
            // issue next 8 kv-line loads (4x current in-flight) + cols two groups ahead
            int4 nkd[8], nvd[8];
#pragma unroll
            for (int j = 0; j < 8; j++) {
                const int4* p = reinterpret_cast<const int4*>(kv + (size_t)ncols[j] * 256 + h * 32);
                nkd[j] = p[0]; nvd[j] = p[1];
            }
            int c2[8];
#pragma unroll
            for (int j = 0; j < 8; j++) c2[j] = (e + 16 + j < cnt) ? csr_col[c0 + e + 16 + j] : 0;

            // compute current 8 scores
            float sc[8];
#pragma unroll
            for (int j = 0; j < 8; j++) {
                float kf[16];
                f32x2 r;
                r = __builtin_amdgcn_cvt_pk_f32_fp8(kd[j].x, false); kf[0] = r[0]; kf[1] = r[1];
                r = __builtin_amdgcn_cvt_pk_f32_fp8(kd[j].x, true);  kf[2] = r[0]; kf[3] = r[1];
                r = __builtin_amdgcn_cvt_pk_f32_fp8(kd[j].y, false); kf[4] = r[0]; kf[5] = r[1];
                r = __builtin_amdgcn_cvt_pk_f32_fp8(kd[j].y, true);  kf[6] = r[0]; kf[7] = r[1];
                r = __builtin_amdgcn_cvt_pk_f32_fp8(kd[j].z, false); kf[8] = r[0]; kf[9] = r[1];
                r = __builtin_amdgcn_cvt_pk_f32_fp8(kd[j].z, true);  kf[10] = r[0]; kf[11] = r[1];
                r = __builtin_amdgcn_cvt_pk_f32_fp8(kd[j].w, false); kf[12] = r[0]; kf[13] = r[1];
                r = __builtin_amdgcn_cvt_pk_f32_fp8(kd[j].w, true);  kf[14] = r[0]; kf[15] = r[1];
                float dot = 0.f;
#pragma unroll
                for (int q2 = 0; q2 < 16; q2++) dot += qf[q2] * kf[q2];
                sc[j] = (e + j < cnt) ? dot * 0.25f : -1e30f;  // 1/sqrt(16)
            }
            const float cm = fmaxf(fmaxf(fmaxf(sc[0], sc[1]), fmaxf(sc[2], sc[3])),
                                   fmaxf(fmaxf(sc[4], sc[5]), fmaxf(sc[6], sc[7])));
            if (e == 0) {
                m = cm;
            } else if (!__all(cm <= m + 8.f)) {   // defer-max: rescale ~never
                const float nm = fmaxf(m, cm);
                const float s8 = __expf(m - nm);
                den *= s8;
#pragma unroll
                for (int i = 0; i < 16; i++) acc[i] *= s8;
                m = nm;
            }
            float psum = 0.f;
#pragma unroll
            for (int j = 0; j < 8; j++) {
                const float pp = (e + j < cnt) ? __expf(sc[j] - m) : 0.f;
                psum += pp;
                f32x2 r;
                r = __builtin_amdgcn_cvt_pk_f32_fp8(vd[j].x, false); acc[0] += pp * r[0]; acc[1] += pp * r[1];
                r = __builtin_amdgcn_cvt_pk_f32_fp8(vd[j].x, true);  acc[2] += pp * r[0]; acc[3] += pp * r[1];
                r = __builtin_amdgcn_cvt_pk_f32_fp8(vd[j].y, false); acc[4] += pp * r[0]; acc[5] += pp * r[1];
                r = __builtin_amdgcn_cvt_pk_f32_fp8(vd[j].y, true);  acc[6] += pp * r[0]; acc[7] += pp * r[1];
                r = __builtin_amdgcn_cvt_pk_f32_fp8(vd[j].z, false); acc[8] += pp * r[0]; acc[9] += pp * r[1];
                r = __builtin_amdgcn_cvt_pk_f32_fp8(vd[j].z, true);  acc[10] += pp * r[0]; acc[11] += pp * r[1];
                r = __builtin_amdgcn_cvt_pk_f32_fp8(vd[j].w, false); acc[12] += pp * r[0]; acc[13] += pp * r[1];
                r = __builtin_amdgcn_cvt_pk_f32_fp8(vd[j].w, true);  acc[14] += pp * r[0]; acc[15] += pp * r[1];
            }
            den += psum;
#pragma unroll
            for (int j = 0; j < 8; j++) { kd[j] = nkd[j]; vd[j] = nvd[j]; ncols[j] = c2[j]; }
        }
        const float inv = 1.f / (den + 1e-9f);
        u16x8 o0, o1;
#pragma unroll
        for (int j = 0; j < 8; j++) { o0[j] = f2bf(acc[j] * inv); o1[j] = f2bf(acc[8 + j] * inv); }
        const int base16 = rl * 128 + h * 16;
        *reinterpret_cast<u16x8*>(&aT[(base16) ^ ((rl & 7) << 3)]) = o0;
        *reinterpret_cast<u16x8*>(&aT[(base16 + 8) ^ ((rl & 7) << 3)]) = o1;
    }
    // permuted global rows for this thread's 4 output rows
    int prow[4];
#pragma unroll
    for (int j = 0; j < 4; j++) prow[j] = perm[rb + m0 + 4 * lg + j];
    // prefetch w1 half0 into regs (T14)
    u16x8 wst[8];
#pragma unroll
    for (int i = 0; i < 8; i++) {
        const int off = i * 2048 + t * 8;
        const int k8 = off >> 10, rem = off & 1023;
        wst[i] = *reinterpret_cast<const u16x8*>(w1p + (k8 << 11) + rem);
    }
    __syncthreads();

    // P1: agg @ wo + residual + LN2
    bf16x8 a[4];
#pragma unroll
    for (int kc = 0; kc < 4; kc++)
        a[kc] = *reinterpret_cast<const bf16x8*>(&aT[(row * 128 + kc * 32 + lg * 8) ^ ((row & 7) << 3)]);
    f32x4 acc[8];
#pragma unroll
    for (int g8 = 0; g8 < 8; g8++) acc[g8] = (f32x4){0.f, 0.f, 0.f, 0.f};
#pragma unroll
    for (int g8 = 0; g8 < 8; g8++)
#pragma unroll
        for (int kc = 0; kc < 4; kc++)
            acc[g8] = __builtin_amdgcn_mfma_f32_16x16x32_bf16(
                a[kc],
                *reinterpret_cast<const bf16x8*>(&wbuf[(((kc << 2) + lg) * 128 + g8 * 16 + lr) << 3]),
                acc[g8], 0, 0, 0);
    float hv[8][4];
#pragma unroll
    for (int g8 = 0; g8 < 8; g8++) {
        const float bias = bo[g8 * 16 + lr];
#pragma unroll
        for (int j = 0; j < 4; j++)
            hv[g8][j] = acc[g8][j] + bias + x[(size_t)prow[j] * HH + g8 * 16 + lr];
    }
    float mu[4], rs[4];
#pragma unroll
    for (int j = 0; j < 4; j++) {
        float s = 0.f, ss = 0.f;
#pragma unroll
        for (int g8 = 0; g8 < 8; g8++) { const float hh = hv[g8][j]; s += hh; ss += hh * hh; }
        s += __shfl_xor(s, 1); s += __shfl_xor(s, 2); s += __shfl_xor(s, 4); s += __shfl_xor(s, 8);
        ss += __shfl_xor(ss, 1); ss += __shfl_xor(ss, 2); ss += __shfl_xor(ss, 4); ss += __shfl_xor(ss, 8);
        mu[j] = s * (1.f / HH);
        rs[j] = rsqrtf(ss * (1.f / HH) - mu[j] * mu[j] + LNEPS);
    }
    __syncthreads();  // aT(agg) + wbuf(wo) reads complete

    // P2: hn -> aT ; ds_write w1h0 ; prefetch w1h1
#pragma unroll
    for (int g8 = 0; g8 < 8; g8++) {
        const float gg = g2[g8 * 16 + lr], bb = bl2[g8 * 16 + lr];
#pragma unroll
        for (int j = 0; j < 4; j++) {
            const int i = m0 + 4 * lg + j;
            aT[(i * 128 + g8 * 16 + lr) ^ ((i & 7) << 3)] = f2bf((hv[g8][j] - mu[j]) * rs[j] * gg + bb);
        }
    }
#pragma unroll
    for (int i = 0; i < 8; i++) {
        const int off = i * 2048 + t * 8;
        *reinterpret_cast<u16x8*>(&wbuf[off]) = wst[i];
    }
#pragma unroll
    for (int i = 0; i < 8; i++) {
        const int off = i * 2048 + t * 8;
        const int k8 = off >> 10, rem = off & 1023;
        wst[i] = *reinterpret_cast<const u16x8*>(w1p + (k8 << 11) + 1024 + rem);
    }
    __syncthreads();

    bf16x8 a2[4];
#pragma unroll
    for (int kc = 0; kc < 4; kc++)
        a2[kc] = *reinterpret_cast<const bf16x8*>(&aT[(row * 128 + kc * 32 + lg * 8) ^ ((row & 7) << 3)]);

    // P3: mlp1 half0 -> tT
#pragma unroll 1
    for (int Gl = 0; Gl < 8; Gl++) {
        f32x4 a1 = (f32x4){0.f, 0.f, 0.f, 0.f};
#pragma unroll
        for (int kc = 0; kc < 4; kc++)
            a1 = __builtin_amdgcn_mfma_f32_16x16x32_bf16(
                a2[kc],
                *reinterpret_cast<const bf16x8*>(&wbuf[(((kc << 2) + lg) * 128 + Gl * 16 + lr) << 3]),
                a1, 0, 0, 0);
        const float bias = b1[Gl * 16 + lr];
#pragma unroll
        for (int j = 0; j < 4; j++) {
            const int i = m0 + 4 * lg + j;
            tT[(i * 256 + Gl * 16 + lr) ^ ((i & 7) << 3)] = f2bf(gelu_tanh(a1[j] + bias));
        }
    }
    __syncthreads();

    // P4: ds_write w1h1 ; prefetch w2h0
#pragma unroll
    for (int i = 0; i < 8; i++) {
        const int off = i * 2048 + t * 8;
        *reinterpret_cast<u16x8*>(&wbuf[off]) = wst[i];
    }
#pragma unroll
    for (int i = 0; i < 8; i++) {
        const int off = i * 2048 + t * 8;
        wst[i] = *reinterpret_cast<const u16x8*>(w2p + off);
    }
    __syncthreads();

    // P5: mlp1 half1 -> tT
#pragma unroll 1
    for (int Gl = 0; Gl < 8; Gl++) {
        const int G = 8 + Gl;
        f32x4 a1 = (f32x4){0.f, 0.f, 0.f, 0.f};
#pragma unroll
        for (int kc = 0; kc < 4; kc++)
            a1 = __builtin_amdgcn_mfma_f32_16x16x32_bf16(
                a2[kc],
                *reinterpret_cast<const bf16x8*>(&wbuf[(((kc << 2) + lg) * 128 + Gl * 16 + lr) << 3]),
                a1, 0, 0, 0);
        const float bias = b1[G * 16 + lr];
#pragma unroll
        for (int j = 0; j < 4; j++) {
            const int i = m0 + 4 * lg + j;
            tT[(i * 256 + G * 16 + lr) ^ ((i & 7) << 3)] = f2bf(gelu_tanh(a1[j] + bias));
        }
    }
    __syncthreads();

    // P6: ds_write w2h0 ; prefetch w2h1
#pragma unroll
    for (int i = 0; i < 8; i++) {
        const int off = i * 2048 + t * 8;
        *reinterpret_cast<u16x8*>(&wbuf[off]) = wst[i];
    }
#pragma unroll
    for (int i = 0; i < 8; i++) {
        const int off = i * 2048 + t * 8;
        wst[i] = *reinterpret_cast<const u16x8*>(w2p + 16384 + off);
    }
    __syncthreads();

    // P7: mlp2 K-half0
    f32x4 acc2[8];
#pragma unroll
    for (int g8 = 0; g8 < 8; g8++) acc2[g8] = (f32x4){0.f, 0.f, 0.f, 0.f};
    {
        bf16x8 a3[4];
#pragma unroll
        for (int kc = 0; kc < 4; kc++)
            a3[kc] = *reinterpret_cast<const bf16x8*>(&tT[(row * 256 + kc * 32 + lg * 8) ^ ((row & 7) << 3)]);
#pragma unroll 1
        for (int g8 = 0; g8 < 8; g8++)
#pragma unroll
            for (int kc = 0; kc < 4; kc++)
                acc2[g8] = __builtin_amdgcn_mfma_f32_16x16x32_bf16(
                    a3[kc],
                    *reinterpret_cast<const bf16x8*>(&wbuf[(((kc << 2) + lg) * 128 + g8 * 16 + lr) << 3]),
                    acc2[g8], 0, 0, 0);
    }
    __syncthreads();

    // P8: ds_write w2h1
#pragma unroll
    for (int i = 0; i < 8; i++) {
        const int off = i * 2048 + t * 8;
        *reinterpret_cast<u16x8*>(&wbuf[off]) = wst[i];
    }
    __syncthreads();

    // P9: mlp2 K-half1 + epilogue
    {
        bf16x8 a3[4];
#pragma unroll
        for (int kc = 0; kc < 4; kc++)
            a3[kc] = *reinterpret_cast<const bf16x8*>(&tT[(row * 256 + 128 + kc * 32 + lg * 8) ^ ((row & 7) << 3)]);
#pragma unroll 1
        for (int g8 = 0; g8 < 8; g8++)
#pragma unroll
            for (int kc = 0; kc < 4; kc++)
                acc2[g8] = __builtin_amdgcn_mfma_f32_16x16x32_bf16(
                    a3[kc],
                    *reinterpret_cast<const bf16x8*>(&wbuf[(((kc << 2) + lg) * 128 + g8 * 16 + lr) << 3]),
                    acc2[g8], 0, 0, 0);
    }
#pragma unroll
    for (int g8 = 0; g8 < 8; g8++) {
        const float bias = b2[g8 * 16 + lr];
#pragma unroll
        for (int j = 0; j < 4; j++)
            out[(size_t)prow[j] * HH + g8 * 16 + lr] = hv[g8][j] + acc2[g8][j] + bias;
    }
}

extern "C" void kernel_launch(void* const* d_in, const int* in_sizes, int n_in,
                              void* d_out, int out_size, void* d_ws, size_t ws_size,
                              hipStream_t stream) {
    const float* x = (const float*)d_in[0];
    const int* erow = (const int*)d_in[1];
    const int* ecol = (const int*)d_in[2];
    const float* ln1g = (const float*)d_in[3];
    const float* ln1b = (const float*)d_in[4];
    const float* wq = (const float*)d_in[5];
    const float* bq = (const float*)d_in[6];
    const float* wk = (const float*)d_in[7];
    const float* bk = (const float*)d_in[8];
    const float* wv = (const float*)d_in[9];
    const float* bv = (const float*)d_in[10];
    const float* wo = (const float*)d_in[11];
    const float* bo = (const float*)d_in[12];
    const float* ln2g = (const float*)d_in[13];
    const float* ln2b = (const float*)d_in[14];
    const float* w1 = (const float*)d_in[15];
    const float* b1 = (const float*)d_in[16];
    const float* w2 = (const float*)d_in[17];
    const float* b2 = (const float*)d_in[18];
    float* out = (float*)d_out;

    unsigned short* qb = (unsigned short*)d_ws;                        // NN*128 ushort (16 MB)
    unsigned char* kv8 = (unsigned char*)(qb + (size_t)NN * HH);       // NN*256 bytes (16 MB)
    unsigned short* wpack = (unsigned short*)(kv8 + (size_t)NN * 256); // 81920 ushorts (wo|w1|w2)
    int* offs = (int*)(wpack + 81920);                                 // NN+1 ints
    int* csr_col = offs + NN + 1;                                      // NE ints (4 MB)
    int* gcur = csr_col + NE;                                          // NB ints
    int* perm = gcur + NB + 2;                                         // NN ints (256 KB)
    unsigned long long* pairs = (unsigned long long*)(perm + NN + 2);  // NB*BCAP (12 MB)

    hipMemsetAsync(gcur, 0, NB * sizeof(int), stream);
    k_qkv_bin<<<768, 256, 0, stream>>>(x, ln1g, ln1b, wq, wk, wv, bq, bk, bv,
                                       qb, kv8, erow, ecol, gcur, pairs);
    k_csr_pack<<<576, 256, 0, stream>>>(pairs, gcur, offs, csr_col, perm,
                                        wo, w1, w2, wpack);
    k_at<<<NN / 64, 256, 0, stream>>>(qb, kv8, offs, csr_col, perm,
                                      wpack, bo, x, ln2g, ln2b,
                                      wpack + 16384, b1, wpack + 49152, b2, out);
}

// Round 21
// 144.893 us; speedup vs baseline: 1.0493x; 1.0493x over previous
//
#include <hip/hip_runtime.h>
#include <math.h>

#define NN 65536
#define HH 128
#define DHH 16
#define NE 1048576
#define HID 256
#define LNEPS 1e-5f
#define NB 256      // buckets for CSR build
#define BCAP 6144   // max edges per bucket (mean 4096, sd 64 -> +32 sd)

typedef __attribute__((ext_vector_type(8))) short bf16x8;
typedef __attribute__((ext_vector_type(8))) unsigned short u16x8;
typedef __attribute__((ext_vector_type(4))) float f32x4;
typedef __attribute__((ext_vector_type(2))) float f32x2;

static __device__ __forceinline__ unsigned short f2bf(float f) {
    union { float f; unsigned u; } c; c.f = f;
    unsigned r = c.u + 0x7fffu + ((c.u >> 16) & 1u);
    return (unsigned short)(r >> 16);
}
static __device__ __forceinline__ float bf2f(unsigned short u) {
    union { unsigned u; float f; } c; c.u = ((unsigned)u) << 16;
    return c.f;
}
// gelu_tanh(x) == x*sigmoid(2c(x+0.044715x^3))  [exact identity]
static __device__ __forceinline__ float gelu_tanh(float x) {
    const float a = -2.302225282f;  // -2*log2(e)*0.7978845608
    const float u = a * (x + 0.044715f * x * x * x);
    const float e = __builtin_amdgcn_exp2f(u);
    return x * __builtin_amdgcn_rcpf(1.f + e);
}

// ---------------- K1: LN1+QKV w/ inline fp32->bf16 panel staging (0..511) ∥ edge bin (512..767) --
__global__ __launch_bounds__(256) void k_qkv_bin(
    const float* __restrict__ x, const float* __restrict__ g, const float* __restrict__ bl,
    const float* __restrict__ wq, const float* __restrict__ wk, const float* __restrict__ wv,
    const float* __restrict__ bq, const float* __restrict__ bk, const float* __restrict__ bv,
    unsigned short* __restrict__ qo, unsigned char* __restrict__ kv8,
    const int* __restrict__ er, const int* __restrict__ ec,
    int* __restrict__ gcur, unsigned long long* __restrict__ pairs) {
    __shared__ int smem4[16384];  // 64 KB arena
    const int t = threadIdx.x;
    if (blockIdx.x < 512) {
        unsigned short* aT = (unsigned short*)smem4;            // 32 KB
        unsigned short* wbuf = (unsigned short*)smem4 + 16384;  // 32 KB
        const int rb = blockIdx.x * 128;
        const int w = t >> 6, l = t & 63;
        {
            const int sr0 = w * 32 + (l >> 2), qd = l & 3;
#pragma unroll 1
            for (int rr = 0; rr < 2; rr++) {
                const int row = sr0 + rr * 16;
                const float4* xr = reinterpret_cast<const float4*>(x + (size_t)(rb + row) * HH) + qd * 8;
                float xa[32]; float s = 0.f, ss = 0.f;
#pragma unroll
                for (int i = 0; i < 8; i++) {
                    float4 v4 = xr[i];
                    xa[i * 4 + 0] = v4.x; xa[i * 4 + 1] = v4.y; xa[i * 4 + 2] = v4.z; xa[i * 4 + 3] = v4.w;
                    s += v4.x + v4.y + v4.z + v4.w;
                    ss += v4.x * v4.x + v4.y * v4.y + v4.z * v4.z + v4.w * v4.w;
                }
                s += __shfl_xor(s, 1); s += __shfl_xor(s, 2);
                ss += __shfl_xor(ss, 1); ss += __shfl_xor(ss, 2);
                const float mu = s * (1.f / HH);
                const float rs = rsqrtf(ss * (1.f / HH) - mu * mu + LNEPS);
#pragma unroll
                for (int c = 0; c < 4; c++) {
                    u16x8 w8;
#pragma unroll
                    for (int j2 = 0; j2 < 8; j2++) {
                        const int d = qd * 32 + c * 8 + j2;
                        w8[j2] = f2bf((xa[c * 8 + j2] - mu) * rs * g[d] + bl[d]);
                    }
                    const int uoff = (row * 128 + qd * 32 + c * 8) ^ ((row & 7) << 3);
                    *reinterpret_cast<u16x8*>(&aT[uoff]) = w8;
                }
            }
            // stage wq panel, converting fp32 -> packed bf16 inline
#pragma unroll
            for (int i = 0; i < 8; i++) {
                const int off = i * 2048 + t * 8;
                const int k8 = off >> 10, n = (off >> 3) & 127;
                u16x8 w8;
#pragma unroll
                for (int j = 0; j < 8; j++) w8[j] = f2bf(wq[(size_t)(k8 * 8 + j) * 128 + n]);
                *reinterpret_cast<u16x8*>(&wbuf[off]) = w8;
            }
        }
        __syncthreads();
        const int lr = l & 15, lg = l >> 4;
        const int row0 = w * 32 + lr;
        const int row1 = w * 32 + 16 + lr;
        bf16x8 a0[4], a1[4];
#pragma unroll
        for (int kc = 0; kc < 4; kc++) {
            a0[kc] = *reinterpret_cast<const bf16x8*>(&aT[(row0 * 128 + kc * 32 + lg * 8) ^ ((row0 & 7) << 3)]);
            a1[kc] = *reinterpret_cast<const bf16x8*>(&aT[(row1 * 128 + kc * 32 + lg * 8) ^ ((row1 & 7) << 3)]);
        }
#pragma unroll 1
        for (int m = 0; m < 3; m++) {
            const float* Bb = (m == 0) ? bq : (m == 1) ? bk : bv;
            f32x4 ac0[8], ac1[8];
#pragma unroll
            for (int g8 = 0; g8 < 8; g8++) { ac0[g8] = (f32x4){0.f,0.f,0.f,0.f}; ac1[g8] = (f32x4){0.f,0.f,0.f,0.f}; }
#pragma unroll
            for (int g8 = 0; g8 < 8; g8++)
#pragma unroll
                for (int kc = 0; kc < 4; kc++) {
                    const bf16x8 bfr = *reinterpret_cast<const bf16x8*>(&wbuf[(((kc << 2) + lg) * 128 + g8 * 16 + lr) << 3]);
                    ac0[g8] = __builtin_amdgcn_mfma_f32_16x16x32_bf16(a0[kc], bfr, ac0[g8], 0, 0, 0);
                    ac1[g8] = __builtin_amdgcn_mfma_f32_16x16x32_bf16(a1[kc], bfr, ac1[g8], 0, 0, 0);
                }
            __syncthreads();
            if (m < 2) {
                const float* nsrcf = (m == 0) ? wk : wv;
#pragma unroll
                for (int i = 0; i < 8; i++) {
                    const int off = i * 2048 + t * 8;
                    const int k8 = off >> 10, n = (off >> 3) & 127;
                    u16x8 w8;
#pragma unroll
                    for (int j = 0; j < 8; j++) w8[j] = f2bf(nsrcf[(size_t)(k8 * 8 + j) * 128 + n]);
                    *reinterpret_cast<u16x8*>(&wbuf[off]) = w8;
                }
            }
#pragma unroll
            for (int g8 = 0; g8 < 8; g8++) {
                const float bias = Bb[g8 * 16 + lr];
#pragma unroll
                for (int j = 0; j < 4; j++) {
                    const int ra = rb + w * 32 + 4 * lg + j;
                    const int rbb = ra + 16;
                    const float y0 = ac0[g8][j] + bias, y1 = ac1[g8][j] + bias;
                    if (m == 0) {
                        qo[(size_t)ra * HH + g8 * 16 + lr] = f2bf(y0);
                        qo[(size_t)rbb * HH + g8 * 16 + lr] = f2bf(y1);
                    } else {
                        const int off = g8 * 32 + lr + ((m == 2) ? 16 : 0);
                        const int pk0 = __builtin_amdgcn_cvt_pk_fp8_f32(y0, y0, 0, false);
                        const int pk1 = __builtin_amdgcn_cvt_pk_fp8_f32(y1, y1, 0, false);
                        kv8[(size_t)ra * 256 + off] = (unsigned char)(pk0 & 0xff);
                        kv8[(size_t)rbb * 256 + off] = (unsigned char)(pk1 & 0xff);
                    }
                }
            }
            if (m < 2) __syncthreads();
        }
    } else {
        int* cnt = smem4;
        int* cur = smem4 + 256;
        int* base = smem4 + 512;
        const int e0 = (blockIdx.x - 512) * 4096;
        cnt[t] = 0;
        __syncthreads();
        int rows[16], cols[16];
#pragma unroll
        for (int i = 0; i < 16; i++) {
            const int e = e0 + i * 256 + t;
            rows[i] = er[e];
            cols[i] = ec[e];
            atomicAdd(&cnt[rows[i] >> 8], 1);
        }
        __syncthreads();
        if (cnt[t] > 0) base[t] = atomicAdd(&gcur[t], cnt[t]);
        cur[t] = 0;
        __syncthreads();
#pragma unroll
        for (int i = 0; i < 16; i++) {
            const int b = rows[i] >> 8;
            const int slot = atomicAdd(&cur[b], 1);
            pairs[(size_t)b * BCAP + base[b] + slot] =
                ((unsigned long long)rows[i] << 32) | (unsigned)cols[i];
        }
    }
}

// ---------------- K2: CSR finalize (0..255) ∥ pack wo/w1/w2 (256..575) ------------
__global__ __launch_bounds__(256) void k_csr_pack(
    const unsigned long long* __restrict__ pairs, const int* __restrict__ gcur,
    int* __restrict__ offs, int* __restrict__ csr_col,
    const float* __restrict__ wo, const float* __restrict__ w1, const float* __restrict__ w2,
    unsigned short* __restrict__ wpack) {
    __shared__ int smem4[7168];
    const int t = threadIdx.x;
    if (blockIdx.x < 256) {
        int* cnt = smem4;
        int* sc = smem4 + 256;
        int* cur = smem4 + 512;
        int* colbuf = smem4 + 768;          // BCAP ints
        const int b = blockIdx.x;
        sc[t] = gcur[t];
        __syncthreads();
        for (int d = 1; d < NB; d <<= 1) {
            int vv = (t >= d) ? sc[t - d] : 0;
            __syncthreads();
            sc[t] += vv;
            __syncthreads();
        }
        const int cbase = (b == 0) ? 0 : sc[b - 1];
        const int tot = gcur[b];
        __syncthreads();
        const unsigned long long* bp = pairs + (size_t)b * BCAP;
        cnt[t] = 0;
        __syncthreads();
        for (int i = t; i < tot; i += 256) {
            const unsigned long long u = bp[i];
            atomicAdd(&cnt[(int)(u >> 32) & 255], 1);
        }
        __syncthreads();
        sc[t] = cnt[t];
        __syncthreads();
        for (int d = 1; d < 256; d <<= 1) {
            int vv = (t >= d) ? sc[t - d] : 0;
            __syncthreads();
            sc[t] += vv;
            __syncthreads();
        }
        const int excl = sc[t] - cnt[t];
        offs[b * 256 + t] = cbase + excl;
        cur[t] = excl;
        if (b == NB - 1 && t == 255) offs[NN] = NE;
        __syncthreads();
        for (int i = t; i < tot; i += 256) {
            const unsigned long long u = bp[i];
            const int r = (int)(u >> 32) & 255;
            const int p = atomicAdd(&cur[r], 1);
            colbuf[p] = (int)(unsigned)u;
        }
        __syncthreads();
        for (int i = t; i < tot; i += 256) csr_col[cbase + i] = colbuf[i];
    } else {
        const int b2 = blockIdx.x - 256;
        const float* src; unsigned short* dst; int N, idx;
        if (b2 < 64)       { src = wo; dst = wpack;          N = 128; idx = b2 * 256 + t; }
        else if (b2 < 192) { src = w1; dst = wpack + 16384;  N = 256; idx = (b2 - 64) * 256 + t; }
        else               { src = w2; dst = wpack + 49152;  N = 128; idx = (b2 - 192) * 256 + t; }
        const int k = idx / N, n = idx % N;
        dst[(((k >> 3) * N + n) << 3) + (k & 7)] = f2bf(src[idx]);
    }
}

// ---------------- K3: fused attention (4-edge-wide pipeline) + wo + res + LN2 + MLP -------------
__global__ __launch_bounds__(256) void k_at(
    const unsigned short* __restrict__ q, const unsigned char* __restrict__ kv,
    const int* __restrict__ offs, const int* __restrict__ csr_col,
    const unsigned short* __restrict__ wop, const float* __restrict__ bo,
    const float* __restrict__ x, const float* __restrict__ g2, const float* __restrict__ bl2,
    const unsigned short* __restrict__ w1p, const float* __restrict__ b1,
    const unsigned short* __restrict__ w2p, const float* __restrict__ b2,
    float* __restrict__ out) {
    __shared__ unsigned short aT[64 * 128];   // 16 KB: agg tile, then hn tile
    __shared__ unsigned short tT[64 * 256];   // 32 KB
    __shared__ unsigned short wbuf[16384];    // 32 KB
    const int t = threadIdx.x;
    const int rb = blockIdx.x * 64;
    const int w = t >> 6, l = t & 63;
    const int m0 = w * 16, lr = l & 15, lg = l >> 4;
    const int row = m0 + lr;

    // stage wo panel up-front (direct)
#pragma unroll
    for (int i = 0; i < 8; i++) {
        const int off = i * 2048 + t * 8;
        *reinterpret_cast<u16x8*>(&wbuf[off]) = *reinterpret_cast<const u16x8*>(wop + off);
    }

    // ---- attention: 2 (row,head) units per thread, 4-edge-wide pipeline -> aT (swizzled bf16) --
#pragma unroll 1
    for (int u = 0; u < 2; u++) {
        const int rl = (t >> 3) + u * 32;        // local row 0..63
        const int arow = rb + rl;
        const int h = t & 7;
        const int c0 = offs[arow];
        const int cnt = offs[arow + 1] - c0;
        int mx = cnt;
#pragma unroll
        for (int d = 8; d < 64; d <<= 1) mx = max(mx, __shfl_xor(mx, d));
        mx = (mx + 3) & ~3;

        float qf[16];
        {
            const u16x8* qp = reinterpret_cast<const u16x8*>(q + (size_t)arow * HH + h * DHH);
            u16x8 q0 = qp[0], q1 = qp[1];
#pragma unroll
            for (int j = 0; j < 8; j++) { qf[j] = bf2f(q0[j]); qf[8 + j] = bf2f(q1[j]); }
        }
        float m = 0.f, den = 0.f;
        float acc[16] = {};

        // prologue: kv for edges 0..3 in flight; cols for edges 4..7 buffered
        int4 kd0, kd1, kd2, kd3, vd0, vd1, vd2, vd3;
        int nc0, nc1, nc2, nc3;
        {
            const int cA = (0 < cnt) ? csr_col[c0 + 0] : 0;
            const int cB = (1 < cnt) ? csr_col[c0 + 1] : 0;
            const int cC = (2 < cnt) ? csr_col[c0 + 2] : 0;
            const int cD = (3 < cnt) ? csr_col[c0 + 3] : 0;
            const int4* pA = reinterpret_cast<const int4*>(kv + (size_t)cA * 256 + h * 32);
            const int4* pB = reinterpret_cast<const int4*>(kv + (size_t)cB * 256 + h * 32);
            const int4* pC = reinterpret_cast<const int4*>(kv + (size_t)cC * 256 + h * 32);
            const int4* pD = reinterpret_cast<const int4*>(kv + (size_t)cD * 256 + h * 32);
            kd0 = pA[0]; vd0 = pA[1]; kd1 = pB[0]; vd1 = pB[1];
            kd2 = pC[0]; vd2 = pC[1]; kd3 = pD[0]; vd3 = pD[1];
            nc0 = (4 < cnt) ? csr_col[c0 + 4] : 0;
            nc1 = (5 < cnt) ? csr_col[c0 + 5] : 0;
            nc2 = (6 < cnt) ? csr_col[c0 + 6] : 0;
            nc3 = (7 < cnt) ? csr_col[c0 + 7] : 0;
        }

        for (int e = 0; e < mx; e += 4) {
            // issue next 4 kv-line loads + cols two groups ahead
            const int4* pA = reinterpret_cast<const int4*>(kv + (size_t)nc0 * 256 + h * 32);
            const int4* pB = reinterpret_cast<const int4*>(kv + (size_t)nc1 * 256 + h * 32);
            const int4* pC = reinterpret_cast<const int4*>(kv + (size_t)nc2 * 256 + h * 32);
            const int4* pD = reinterpret_cast<const int4*>(kv + (size_t)nc3 * 256 + h * 32);
            const int4 nkd0 = pA[0], nvd0 = pA[1];
            const int4 nkd1 = pB[0], nvd1 = pB[1];
            const int4 nkd2 = pC[0], nvd2 = pC[1];
            const int4 nkd3 = pD[0], nvd3 = pD[1];
            const int c20 = (e + 8 < cnt) ? csr_col[c0 + e + 8] : 0;
            const int c21 = (e + 9 < cnt) ? csr_col[c0 + e + 9] : 0;
            const int c22 = (e + 10 < cnt) ? csr_col[c0 + e + 10] : 0;
            const int c23 = (e + 11 < cnt) ? csr_col[c0 + e + 11] : 0;

            // compute current 4 scores
            float sc[4];
            const int4 kds[4] = {kd0, kd1, kd2, kd3};
#pragma unroll
            for (int j = 0; j < 4; j++) {
                float kf[16];
                f32x2 r;
                r = __builtin_amdgcn_cvt_pk_f32_fp8(kds[j].x, false); kf[0] = r[0]; kf[1] = r[1];
                r = __builtin_amdgcn_cvt_pk_f32_fp8(kds[j].x, true);  kf[2] = r[0]; kf[3] = r[1];
                r = __builtin_amdgcn_cvt_pk_f32_fp8(kds[j].y, false); kf[4] = r[0]; kf[5] = r[1];
                r = __builtin_amdgcn_cvt_pk_f32_fp8(kds[j].y, true);  kf[6] = r[0]; kf[7] = r[1];
                r = __builtin_amdgcn_cvt_pk_f32_fp8(kds[j].z, false); kf[8] = r[0]; kf[9] = r[1];
                r = __builtin_amdgcn_cvt_pk_f32_fp8(kds[j].z, true);  kf[10] = r[0]; kf[11] = r[1];
                r = __builtin_amdgcn_cvt_pk_f32_fp8(kds[j].w, false); kf[12] = r[0]; kf[13] = r[1];
                r = __builtin_amdgcn_cvt_pk_f32_fp8(kds[j].w, true);  kf[14] = r[0]; kf[15] = r[1];
                float dot = 0.f;
#pragma unroll
                for (int q2 = 0; q2 < 16; q2++) dot += qf[q2] * kf[q2];
                sc[j] = (e + j < cnt) ? dot * 0.25f : -1e30f;  // 1/sqrt(16)
            }
            const float cm = fmaxf(fmaxf(sc[0], sc[1]), fmaxf(sc[2], sc[3]));
            if (e == 0) {
                m = cm;
            } else if (!__all(cm <= m + 8.f)) {   // defer-max: rescale ~never
                const float nm = fmaxf(m, cm);
                const float s8 = __expf(m - nm);
                den *= s8;
#pragma unroll
                for (int i = 0; i < 16; i++) acc[i] *= s8;
                m = nm;
            }
            const int4 vds[4] = {vd0, vd1, vd2, vd3};
            float psum = 0.f;
#pragma unroll
            for (int j = 0; j < 4; j++) {
                const float pp = (e + j < cnt) ? __expf(sc[j] - m) : 0.f;
                psum += pp;
                f32x2 r;
                r = __builtin_amdgcn_cvt_pk_f32_fp8(vds[j].x, false); acc[0] += pp * r[0]; acc[1] += pp * r[1];
                r = __builtin_amdgcn_cvt_pk_f32_fp8(vds[j].x, true);  acc[2] += pp * r[0]; acc[3] += pp * r[1];
                r = __builtin_amdgcn_cvt_pk_f32_fp8(vds[j].y, false); acc[4] += pp * r[0]; acc[5] += pp * r[1];
                r = __builtin_amdgcn_cvt_pk_f32_fp8(vds[j].y, true);  acc[6] += pp * r[0]; acc[7] += pp * r[1];
                r = __builtin_amdgcn_cvt_pk_f32_fp8(vds[j].z, false); acc[8] += pp * r[0]; acc[9] += pp * r[1];
                r = __builtin_amdgcn_cvt_pk_f32_fp8(vds[j].z, true);  acc[10] += pp * r[0]; acc[11] += pp * r[1];
                r = __builtin_amdgcn_cvt_pk_f32_fp8(vds[j].w, false); acc[12] += pp * r[0]; acc[13] += pp * r[1];
                r = __builtin_amdgcn_cvt_pk_f32_fp8(vds[j].w, true);  acc[14] += pp * r[0]; acc[15] += pp * r[1];
            }
            den += psum;
            kd0 = nkd0; vd0 = nvd0; kd1 = nkd1; vd1 = nvd1;
            kd2 = nkd2; vd2 = nvd2; kd3 = nkd3; vd3 = nvd3;
            nc0 = c20; nc1 = c21; nc2 = c22; nc3 = c23;
        }
        const float inv = 1.f / (den + 1e-9f);
        u16x8 o0, o1;
#pragma unroll
        for (int j = 0; j < 8; j++) { o0[j] = f2bf(acc[j] * inv); o1[j] = f2bf(acc[8 + j] * inv); }
        const int base16 = rl * 128 + h * 16;
        *reinterpret_cast<u16x8*>(&aT[(base16) ^ ((rl & 7) << 3)]) = o0;
        *reinterpret_cast<u16x8*>(&aT[(base16 + 8) ^ ((rl & 7) << 3)]) = o1;
    }
    // prefetch w1 half0 into regs (T14)
    u16x8 wst[8];
#pragma unroll
    for (int i = 0; i < 8; i++) {
        const int off = i * 2048 + t * 8;
        const int k8 = off >> 10, rem = off & 1023;
        wst[i] = *reinterpret_cast<const u16x8*>(w1p + (k8 << 11) + rem);
    }
    __syncthreads();

    // P1: agg @ wo + residual + LN2
    bf16x8 a[4];
#pragma unroll
    for (int kc = 0; kc < 4; kc++)
        a[kc] = *reinterpret_cast<const bf16x8*>(&aT[(row * 128 + kc * 32 + lg * 8) ^ ((row & 7) << 3)]);
    f32x4 acc[8];
#pragma unroll
    for (int g8 = 0; g8 < 8; g8++) acc[g8] = (f32x4){0.f, 0.f, 0.f, 0.f};
#pragma unroll
    for (int g8 = 0; g8 < 8; g8++)
#pragma unroll
        for (int kc = 0; kc < 4; kc++)
            acc[g8] = __builtin_amdgcn_mfma_f32_16x16x32_bf16(
                a[kc],
                *reinterpret_cast<const bf16x8*>(&wbuf[(((kc << 2) + lg) * 128 + g8 * 16 + lr) << 3]),
                acc[g8], 0, 0, 0);
    float hv[8][4];
#pragma unroll
    for (int g8 = 0; g8 < 8; g8++) {
        const float bias = bo[g8 * 16 + lr];
#pragma unroll
        for (int j = 0; j < 4; j++)
            hv[g8][j] = acc[g8][j] + bias + x[(size_t)(rb + m0 + 4 * lg + j) * HH + g8 * 16 + lr];
    }
    float mu[4], rs[4];
#pragma unroll
    for (int j = 0; j < 4; j++) {
        float s = 0.f, ss = 0.f;
#pragma unroll
        for (int g8 = 0; g8 < 8; g8++) { const float hh = hv[g8][j]; s += hh; ss += hh * hh; }
        s += __shfl_xor(s, 1); s += __shfl_xor(s, 2); s += __shfl_xor(s, 4); s += __shfl_xor(s, 8);
        ss += __shfl_xor(ss, 1); ss += __shfl_xor(ss, 2); ss += __shfl_xor(ss, 4); ss += __shfl_xor(ss, 8);
        mu[j] = s * (1.f / HH);
        rs[j] = rsqrtf(ss * (1.f / HH) - mu[j] * mu[j] + LNEPS);
    }
    __syncthreads();  // aT(agg) + wbuf(wo) reads complete

    // P2: hn -> aT ; ds_write w1h0 ; prefetch w1h1
#pragma unroll
    for (int g8 = 0; g8 < 8; g8++) {
        const float gg = g2[g8 * 16 + lr], bb = bl2[g8 * 16 + lr];
#pragma unroll
        for (int j = 0; j < 4; j++) {
            const int i = m0 + 4 * lg + j;
            aT[(i * 128 + g8 * 16 + lr) ^ ((i & 7) << 3)] = f2bf((hv[g8][j] - mu[j]) * rs[j] * gg + bb);
        }
    }
#pragma unroll
    for (int i = 0; i < 8; i++) {
        const int off = i * 2048 + t * 8;
        *reinterpret_cast<u16x8*>(&wbuf[off]) = wst[i];
    }
#pragma unroll
    for (int i = 0; i < 8; i++) {
        const int off = i * 2048 + t * 8;
        const int k8 = off >> 10, rem = off & 1023;
        wst[i] = *reinterpret_cast<const u16x8*>(w1p + (k8 << 11) + 1024 + rem);
    }
    __syncthreads();

    bf16x8 a2[4];
#pragma unroll
    for (int kc = 0; kc < 4; kc++)
        a2[kc] = *reinterpret_cast<const bf16x8*>(&aT[(row * 128 + kc * 32 + lg * 8) ^ ((row & 7) << 3)]);

    // P3: mlp1 half0 -> tT
#pragma unroll 1
    for (int Gl = 0; Gl < 8; Gl++) {
        f32x4 a1 = (f32x4){0.f, 0.f, 0.f, 0.f};
#pragma unroll
        for (int kc = 0; kc < 4; kc++)
            a1 = __builtin_amdgcn_mfma_f32_16x16x32_bf16(
                a2[kc],
                *reinterpret_cast<const bf16x8*>(&wbuf[(((kc << 2) + lg) * 128 + Gl * 16 + lr) << 3]),
                a1, 0, 0, 0);
        const float bias = b1[Gl * 16 + lr];
#pragma unroll
        for (int j = 0; j < 4; j++) {
            const int i = m0 + 4 * lg + j;
            tT[(i * 256 + Gl * 16 + lr) ^ ((i & 7) << 3)] = f2bf(gelu_tanh(a1[j] + bias));
        }
    }
    __syncthreads();

    // P4: ds_write w1h1 ; prefetch w2h0
#pragma unroll
    for (int i = 0; i < 8; i++) {
        const int off = i * 2048 + t * 8;
        *reinterpret_cast<u16x8*>(&wbuf[off]) = wst[i];
    }
#pragma unroll
    for (int i = 0; i < 8; i++) {
        const int off = i * 2048 + t * 8;
        wst[i] = *reinterpret_cast<const u16x8*>(w2p + off);
    }
    __syncthreads();

    // P5: mlp1 half1 -> tT
#pragma unroll 1
    for (int Gl = 0; Gl < 8; Gl++) {
        const int G = 8 + Gl;
        f32x4 a1 = (f32x4){0.f, 0.f, 0.f, 0.f};
#pragma unroll
        for (int kc = 0; kc < 4; kc++)
            a1 = __builtin_amdgcn_mfma_f32_16x16x32_bf16(
                a2[kc],
                *reinterpret_cast<const bf16x8*>(&wbuf[(((kc << 2) + lg) * 128 + Gl * 16 + lr) << 3]),
                a1, 0, 0, 0);
        const float bias = b1[G * 16 + lr];
#pragma unroll
        for (int j = 0; j < 4; j++) {
            const int i = m0 + 4 * lg + j;
            tT[(i * 256 + G * 16 + lr) ^ ((i & 7) << 3)] = f2bf(gelu_tanh(a1[j] + bias));
        }
    }
    __syncthreads();

    // P6: ds_write w2h0 ; prefetch w2h1
#pragma unroll
    for (int i = 0; i < 8; i++) {
        const int off = i * 2048 + t * 8;
        *reinterpret_cast<u16x8*>(&wbuf[off]) = wst[i];
    }
#pragma unroll
    for (int i = 0; i < 8; i++) {
        const int off = i * 2048 + t * 8;
        wst[i] = *reinterpret_cast<const u16x8*>(w2p + 16384 + off);
    }
    __syncthreads();

    // P7: mlp2 K-half0
    f32x4 acc2[8];
#pragma unroll
    for (int g8 = 0; g8 < 8; g8++) acc2[g8] = (f32x4){0.f, 0.f, 0.f, 0.f};
    {
        bf16x8 a3[4];
#pragma unroll
        for (int kc = 0; kc < 4; kc++)
            a3[kc] = *reinterpret_cast<const bf16x8*>(&tT[(row * 256 + kc * 32 + lg * 8) ^ ((row & 7) << 3)]);
#pragma unroll 1
        for (int g8 = 0; g8 < 8; g8++)
#pragma unroll
            for (int kc = 0; kc < 4; kc++)
                acc2[g8] = __builtin_amdgcn_mfma_f32_16x16x32_bf16(
                    a3[kc],
                    *reinterpret_cast<const bf16x8*>(&wbuf[(((kc << 2) + lg) * 128 + g8 * 16 + lr) << 3]),
                    acc2[g8], 0, 0, 0);
    }
    __syncthreads();

    // P8: ds_write w2h1
#pragma unroll
    for (int i = 0; i < 8; i++) {
        const int off = i * 2048 + t * 8;
        *reinterpret_cast<u16x8*>(&wbuf[off]) = wst[i];
    }
    __syncthreads();

    // P9: mlp2 K-half1 + epilogue
    {
        bf16x8 a3[4];
#pragma unroll
        for (int kc = 0; kc < 4; kc++)
            a3[kc] = *reinterpret_cast<const bf16x8*>(&tT[(row * 256 + 128 + kc * 32 + lg * 8) ^ ((row & 7) << 3)]);
#pragma unroll 1
        for (int g8 = 0; g8 < 8; g8++)
#pragma unroll
            for (int kc = 0; kc < 4; kc++)
                acc2[g8] = __builtin_amdgcn_mfma_f32_16x16x32_bf16(
                    a3[kc],
                    *reinterpret_cast<const bf16x8*>(&wbuf[(((kc << 2) + lg) * 128 + g8 * 16 + lr) << 3]),
                    acc2[g8], 0, 0, 0);
    }
#pragma unroll
    for (int g8 = 0; g8 < 8; g8++) {
        const float bias = b2[g8 * 16 + lr];
#pragma unroll
        for (int j = 0; j < 4; j++)
            out[(size_t)(rb + m0 + 4 * lg + j) * HH + g8 * 16 + lr] = hv[g8][j] + acc2[g8][j] + bias;
    }
}

extern "C" void kernel_launch(void* const* d_in, const int* in_sizes, int n_in,
                              void* d_out, int out_size, void* d_ws, size_t ws_size,
                              hipStream_t stream) {
    const float* x = (const float*)d_in[0];
    const int* erow = (const int*)d_in[1];
    const int* ecol = (const int*)d_in[2];
    const float* ln1g = (const float*)d_in[3];
    const float* ln1b = (const float*)d_in[4];
    const float* wq = (const float*)d_in[5];
    const float* bq = (const float*)d_in[6];
    const float* wk = (const float*)d_in[7];
    const float* bk = (const float*)d_in[8];
    const float* wv = (const float*)d_in[9];
    const float* bv = (const float*)d_in[10];
    const float* wo = (const float*)d_in[11];
    const float* bo = (const float*)d_in[12];
    const float* ln2g = (const float*)d_in[13];
    const float* ln2b = (const float*)d_in[14];
    const float* w1 = (const float*)d_in[15];
    const float* b1 = (const float*)d_in[16];
    const float* w2 = (const float*)d_in[17];
    const float* b2 = (const float*)d_in[18];
    float* out = (float*)d_out;

    unsigned short* qb = (unsigned short*)d_ws;                        // NN*128 ushort (16 MB)
    unsigned char* kv8 = (unsigned char*)(qb + (size_t)NN * HH);       // NN*256 bytes (16 MB)
    unsigned short* wpack = (unsigned short*)(kv8 + (size_t)NN * 256); // 81920 ushorts (wo|w1|w2)
    int* offs = (int*)(wpack + 81920);                                 // NN+1 ints
    int* csr_col = offs + NN + 1;                                      // NE ints (4 MB)
    int* gcur = csr_col + NE;                                          // NB ints
    unsigned long long* pairs = (unsigned long long*)(gcur + NB + 2);  // NB*BCAP (12 MB)

    hipMemsetAsync(gcur, 0, NB * sizeof(int), stream);
    k_qkv_bin<<<768, 256, 0, stream>>>(x, ln1g, ln1b, wq, wk, wv, bq, bk, bv,
                                       qb, kv8, erow, ecol, gcur, pairs);
    k_csr_pack<<<576, 256, 0, stream>>>(pairs, gcur, offs, csr_col,
                                        wo, w1, w2, wpack);
    k_at<<<NN / 64, 256, 0, stream>>>(qb, kv8, offs, csr_col,
                                      wpack, bo, x, ln2g, ln2b,
                                      wpack + 16384, b1, wpack + 49152, b2, out);
}

// Round 22
// 128.982 us; speedup vs baseline: 1.1787x; 1.1234x over previous
//
#include <hip/hip_runtime.h>
#include <math.h>

#define NN 65536
#define HH 128
#define DHH 16
#define NE 1048576
#define HID 256
#define LNEPS 1e-5f
#define NB 256      // buckets for CSR build
#define BCAP 6144   // max edges per bucket (mean 4096, sd 64 -> +32 sd)

typedef __attribute__((ext_vector_type(8))) short bf16x8;
typedef __attribute__((ext_vector_type(8))) unsigned short u16x8;
typedef __attribute__((ext_vector_type(4))) float f32x4;
typedef __attribute__((ext_vector_type(2))) float f32x2;

static __device__ __forceinline__ unsigned short f2bf(float f) {
    union { float f; unsigned u; } c; c.f = f;
    unsigned r = c.u + 0x7fffu + ((c.u >> 16) & 1u);
    return (unsigned short)(r >> 16);
}
static __device__ __forceinline__ float bf2f(unsigned short u) {
    union { unsigned u; float f; } c; c.u = ((unsigned)u) << 16;
    return c.f;
}
// gelu_tanh(x) == x*sigmoid(2c(x+0.044715x^3))  [exact identity]
static __device__ __forceinline__ float gelu_tanh(float x) {
    const float a = -2.302225282f;  // -2*log2(e)*0.7978845608
    const float u = a * (x + 0.044715f * x * x * x);
    const float e = __builtin_amdgcn_exp2f(u);
    return x * __builtin_amdgcn_rcpf(1.f + e);
}

// ---------------- K1: LN1+QKV w/ inline fp32->bf16 panel staging (0..511) ∥ edge bin (512..767) --
__global__ __launch_bounds__(256) void k_qkv_bin(
    const float* __restrict__ x, const float* __restrict__ g, const float* __restrict__ bl,
    const float* __restrict__ wq, const float* __restrict__ wk, const float* __restrict__ wv,
    const float* __restrict__ bq, const float* __restrict__ bk, const float* __restrict__ bv,
    unsigned short* __restrict__ qo, unsigned char* __restrict__ kv8,
    const int* __restrict__ er, const int* __restrict__ ec,
    int* __restrict__ gcur, unsigned long long* __restrict__ pairs) {
    __shared__ int smem4[16384];  // 64 KB arena
    const int t = threadIdx.x;
    if (blockIdx.x < 512) {
        unsigned short* aT = (unsigned short*)smem4;            // 32 KB
        unsigned short* wbuf = (unsigned short*)smem4 + 16384;  // 32 KB
        const int rb = blockIdx.x * 128;
        const int w = t >> 6, l = t & 63;
        {
            const int sr0 = w * 32 + (l >> 2), qd = l & 3;
#pragma unroll 1
            for (int rr = 0; rr < 2; rr++) {
                const int row = sr0 + rr * 16;
                const float4* xr = reinterpret_cast<const float4*>(x + (size_t)(rb + row) * HH) + qd * 8;
                float xa[32]; float s = 0.f, ss = 0.f;
#pragma unroll
                for (int i = 0; i < 8; i++) {
                    float4 v4 = xr[i];
                    xa[i * 4 + 0] = v4.x; xa[i * 4 + 1] = v4.y; xa[i * 4 + 2] = v4.z; xa[i * 4 + 3] = v4.w;
                    s += v4.x + v4.y + v4.z + v4.w;
                    ss += v4.x * v4.x + v4.y * v4.y + v4.z * v4.z + v4.w * v4.w;
                }
                s += __shfl_xor(s, 1); s += __shfl_xor(s, 2);
                ss += __shfl_xor(ss, 1); ss += __shfl_xor(ss, 2);
                const float mu = s * (1.f / HH);
                const float rs = rsqrtf(ss * (1.f / HH) - mu * mu + LNEPS);
#pragma unroll
                for (int c = 0; c < 4; c++) {
                    u16x8 w8;
#pragma unroll
                    for (int j2 = 0; j2 < 8; j2++) {
                        const int d = qd * 32 + c * 8 + j2;
                        w8[j2] = f2bf((xa[c * 8 + j2] - mu) * rs * g[d] + bl[d]);
                    }
                    const int uoff = (row * 128 + qd * 32 + c * 8) ^ ((row & 7) << 3);
                    *reinterpret_cast<u16x8*>(&aT[uoff]) = w8;
                }
            }
            // stage wq panel, converting fp32 -> packed bf16 inline
#pragma unroll
            for (int i = 0; i < 8; i++) {
                const int off = i * 2048 + t * 8;
                const int k8 = off >> 10, n = (off >> 3) & 127;
                u16x8 w8;
#pragma unroll
                for (int j = 0; j < 8; j++) w8[j] = f2bf(wq[(size_t)(k8 * 8 + j) * 128 + n]);
                *reinterpret_cast<u16x8*>(&wbuf[off]) = w8;
            }
        }
        __syncthreads();
        const int lr = l & 15, lg = l >> 4;
        const int row0 = w * 32 + lr;
        const int row1 = w * 32 + 16 + lr;
        bf16x8 a0[4], a1[4];
#pragma unroll
        for (int kc = 0; kc < 4; kc++) {
            a0[kc] = *reinterpret_cast<const bf16x8*>(&aT[(row0 * 128 + kc * 32 + lg * 8) ^ ((row0 & 7) << 3)]);
            a1[kc] = *reinterpret_cast<const bf16x8*>(&aT[(row1 * 128 + kc * 32 + lg * 8) ^ ((row1 & 7) << 3)]);
        }
#pragma unroll 1
        for (int m = 0; m < 3; m++) {
            const float* Bb = (m == 0) ? bq : (m == 1) ? bk : bv;
            f32x4 ac0[8], ac1[8];
#pragma unroll
            for (int g8 = 0; g8 < 8; g8++) { ac0[g8] = (f32x4){0.f,0.f,0.f,0.f}; ac1[g8] = (f32x4){0.f,0.f,0.f,0.f}; }
#pragma unroll
            for (int g8 = 0; g8 < 8; g8++)
#pragma unroll
                for (int kc = 0; kc < 4; kc++) {
                    const bf16x8 bfr = *reinterpret_cast<const bf16x8*>(&wbuf[(((kc << 2) + lg) * 128 + g8 * 16 + lr) << 3]);
                    ac0[g8] = __builtin_amdgcn_mfma_f32_16x16x32_bf16(a0[kc], bfr, ac0[g8], 0, 0, 0);
                    ac1[g8] = __builtin_amdgcn_mfma_f32_16x16x32_bf16(a1[kc], bfr, ac1[g8], 0, 0, 0);
                }
            __syncthreads();
            if (m < 2) {
                const float* nsrcf = (m == 0) ? wk : wv;
#pragma unroll
                for (int i = 0; i < 8; i++) {
                    const int off = i * 2048 + t * 8;
                    const int k8 = off >> 10, n = (off >> 3) & 127;
                    u16x8 w8;
#pragma unroll
                    for (int j = 0; j < 8; j++) w8[j] = f2bf(nsrcf[(size_t)(k8 * 8 + j) * 128 + n]);
                    *reinterpret_cast<u16x8*>(&wbuf[off]) = w8;
                }
            }
#pragma unroll
            for (int g8 = 0; g8 < 8; g8++) {
                const float bias = Bb[g8 * 16 + lr];
#pragma unroll
                for (int j = 0; j < 4; j++) {
                    const int ra = rb + w * 32 + 4 * lg + j;
                    const int rbb = ra + 16;
                    const float y0 = ac0[g8][j] + bias, y1 = ac1[g8][j] + bias;
                    if (m == 0) {
                        qo[(size_t)ra * HH + g8 * 16 + lr] = f2bf(y0);
                        qo[(size_t)rbb * HH + g8 * 16 + lr] = f2bf(y1);
                    } else {
                        const int off = g8 * 32 + lr + ((m == 2) ? 16 : 0);
                        const int pk0 = __builtin_amdgcn_cvt_pk_fp8_f32(y0, y0, 0, false);
                        const int pk1 = __builtin_amdgcn_cvt_pk_fp8_f32(y1, y1, 0, false);
                        kv8[(size_t)ra * 256 + off] = (unsigned char)(pk0 & 0xff);
                        kv8[(size_t)rbb * 256 + off] = (unsigned char)(pk1 & 0xff);
                    }
                }
            }
            if (m < 2) __syncthreads();
        }
    } else {
        int* cnt = smem4;
        int* cur = smem4 + 256;
        int* base = smem4 + 512;
        const int e0 = (blockIdx.x - 512) * 4096;
        cnt[t] = 0;
        __syncthreads();
        int rows[16], cols[16];
#pragma unroll
        for (int i = 0; i < 16; i++) {
            const int e = e0 + i * 256 + t;
            rows[i] = er[e];
            cols[i] = ec[e];
            atomicAdd(&cnt[rows[i] >> 8], 1);
        }
        __syncthreads();
        if (cnt[t] > 0) base[t] = atomicAdd(&gcur[t], cnt[t]);
        cur[t] = 0;
        __syncthreads();
#pragma unroll
        for (int i = 0; i < 16; i++) {
            const int b = rows[i] >> 8;
            const int slot = atomicAdd(&cur[b], 1);
            pairs[(size_t)b * BCAP + base[b] + slot] =
                ((unsigned long long)rows[i] << 32) | (unsigned)cols[i];
        }
    }
}

// ---------------- K2: CSR finalize (0..255) ∥ pack wo/w1/w2 (256..575) ------------
__global__ __launch_bounds__(256) void k_csr_pack(
    const unsigned long long* __restrict__ pairs, const int* __restrict__ gcur,
    int* __restrict__ offs, int* __restrict__ csr_col,
    const float* __restrict__ wo, const float* __restrict__ w1, const float* __restrict__ w2,
    unsigned short* __restrict__ wpack) {
    __shared__ int smem4[7168];
    const int t = threadIdx.x;
    if (blockIdx.x < 256) {
        int* cnt = smem4;
        int* sc = smem4 + 256;
        int* cur = smem4 + 512;
        int* colbuf = smem4 + 768;          // BCAP ints
        const int b = blockIdx.x;
        sc[t] = gcur[t];
        __syncthreads();
        for (int d = 1; d < NB; d <<= 1) {
            int vv = (t >= d) ? sc[t - d] : 0;
            __syncthreads();
            sc[t] += vv;
            __syncthreads();
        }
        const int cbase = (b == 0) ? 0 : sc[b - 1];
        const int tot = gcur[b];
        __syncthreads();
        const unsigned long long* bp = pairs + (size_t)b * BCAP;
        cnt[t] = 0;
        __syncthreads();
        for (int i = t; i < tot; i += 256) {
            const unsigned long long u = bp[i];
            atomicAdd(&cnt[(int)(u >> 32) & 255], 1);
        }
        __syncthreads();
        sc[t] = cnt[t];
        __syncthreads();
        for (int d = 1; d < 256; d <<= 1) {
            int vv = (t >= d) ? sc[t - d] : 0;
            __syncthreads();
            sc[t] += vv;
            __syncthreads();
        }
        const int excl = sc[t] - cnt[t];
        offs[b * 256 + t] = cbase + excl;
        cur[t] = excl;
        if (b == NB - 1 && t == 255) offs[NN] = NE;
        __syncthreads();
        for (int i = t; i < tot; i += 256) {
            const unsigned long long u = bp[i];
            const int r = (int)(u >> 32) & 255;
            const int p = atomicAdd(&cur[r], 1);
            colbuf[p] = (int)(unsigned)u;
        }
        __syncthreads();
        for (int i = t; i < tot; i += 256) csr_col[cbase + i] = colbuf[i];
    } else {
        const int b2 = blockIdx.x - 256;
        const float* src; unsigned short* dst; int N, idx;
        if (b2 < 64)       { src = wo; dst = wpack;          N = 128; idx = b2 * 256 + t; }
        else if (b2 < 192) { src = w1; dst = wpack + 16384;  N = 256; idx = (b2 - 64) * 256 + t; }
        else               { src = w2; dst = wpack + 49152;  N = 128; idx = (b2 - 192) * 256 + t; }
        const int k = idx / N, n = idx % N;
        dst[(((k >> 3) * N + n) << 3) + (k & 7)] = f2bf(src[idx]);
    }
}

// ---------------- K3: fused attention + wo + res + LN2 + MLP — 40KB LDS, 4 blocks/CU ------------
__global__ __launch_bounds__(256, 4) void k_at(
    const unsigned short* __restrict__ q, const unsigned char* __restrict__ kv,
    const int* __restrict__ offs, const int* __restrict__ csr_col,
    const unsigned short* __restrict__ wop, const float* __restrict__ bo,
    const float* __restrict__ x, const float* __restrict__ g2, const float* __restrict__ bl2,
    const unsigned short* __restrict__ w1p, const float* __restrict__ b1,
    const unsigned short* __restrict__ w2p, const float* __restrict__ b2,
    float* __restrict__ out) {
    __shared__ unsigned short aT[64 * 128];   // 16 KB: agg tile, then hn tile
    __shared__ unsigned short tT[64 * 64];    // 8 KB: one mlp1 N-quarter
    __shared__ unsigned short wbuf[8192];     // 16 KB: current weight chunk
    const int t = threadIdx.x;
    const int rb = blockIdx.x * 64;
    const int w = t >> 6, l = t & 63;
    const int m0 = w * 16, lr = l & 15, lg = l >> 4;
    const int row = m0 + lr;

    // stage wo K-half 0 up-front (contiguous 16 KB)
#pragma unroll
    for (int i = 0; i < 4; i++) {
        const int off = i * 2048 + t * 8;
        *reinterpret_cast<u16x8*>(&wbuf[off]) = *reinterpret_cast<const u16x8*>(wop + off);
    }

    // ---- attention: 2 (row,head) units per thread (round-16 2-wide pipeline) -> aT -------------
#pragma unroll 1
    for (int u = 0; u < 2; u++) {
        const int rl = (t >> 3) + u * 32;        // local row 0..63
        const int arow = rb + rl;
        const int h = t & 7;
        const int c0 = offs[arow];
        const int cnt = offs[arow + 1] - c0;
        int mx = cnt;
#pragma unroll
        for (int d = 8; d < 64; d <<= 1) mx = max(mx, __shfl_xor(mx, d));
        mx = (mx + 1) & ~1;

        float qf[16];
        {
            const u16x8* qp = reinterpret_cast<const u16x8*>(q + (size_t)arow * HH + h * DHH);
            u16x8 q0 = qp[0], q1 = qp[1];
#pragma unroll
            for (int j = 0; j < 8; j++) { qf[j] = bf2f(q0[j]); qf[8 + j] = bf2f(q1[j]); }
        }
        float m = 0.f, den = 0.f;
        float acc[16] = {};

        int colA = (0 < cnt) ? csr_col[c0] : 0;
        int colB = (1 < cnt) ? csr_col[c0 + 1] : 0;
        const int4* pA = reinterpret_cast<const int4*>(kv + (size_t)colA * 256 + h * 32);
        const int4* pB = reinterpret_cast<const int4*>(kv + (size_t)colB * 256 + h * 32);
        int4 kdA = pA[0], vdA = pA[1];
        int4 kdB = pB[0], vdB = pB[1];
        int colC = (2 < cnt) ? csr_col[c0 + 2] : 0;
        int colD = (3 < cnt) ? csr_col[c0 + 3] : 0;

        for (int e = 0; e < mx; e += 2) {
            const int4* pC = reinterpret_cast<const int4*>(kv + (size_t)colC * 256 + h * 32);
            const int4* pD = reinterpret_cast<const int4*>(kv + (size_t)colD * 256 + h * 32);
            const int4 nkdA = pC[0], nvdA = pC[1];
            const int4 nkdB = pD[0], nvdB = pD[1];
            const int ncolC = ((e + 4) < cnt) ? csr_col[c0 + e + 4] : 0;
            const int ncolD = ((e + 5) < cnt) ? csr_col[c0 + e + 5] : 0;

            const bool act0 = e < cnt, act1 = (e + 1) < cnt;
            float kfA[16], kfB[16];
            {
                f32x2 r;
                r = __builtin_amdgcn_cvt_pk_f32_fp8(kdA.x, false); kfA[0] = r[0]; kfA[1] = r[1];
                r = __builtin_amdgcn_cvt_pk_f32_fp8(kdA.x, true);  kfA[2] = r[0]; kfA[3] = r[1];
                r = __builtin_amdgcn_cvt_pk_f32_fp8(kdA.y, false); kfA[4] = r[0]; kfA[5] = r[1];
                r = __builtin_amdgcn_cvt_pk_f32_fp8(kdA.y, true);  kfA[6] = r[0]; kfA[7] = r[1];
                r = __builtin_amdgcn_cvt_pk_f32_fp8(kdA.z, false); kfA[8] = r[0]; kfA[9] = r[1];
                r = __builtin_amdgcn_cvt_pk_f32_fp8(kdA.z, true);  kfA[10] = r[0]; kfA[11] = r[1];
                r = __builtin_amdgcn_cvt_pk_f32_fp8(kdA.w, false); kfA[12] = r[0]; kfA[13] = r[1];
                r = __builtin_amdgcn_cvt_pk_f32_fp8(kdA.w, true);  kfA[14] = r[0]; kfA[15] = r[1];
                r = __builtin_amdgcn_cvt_pk_f32_fp8(kdB.x, false); kfB[0] = r[0]; kfB[1] = r[1];
                r = __builtin_amdgcn_cvt_pk_f32_fp8(kdB.x, true);  kfB[2] = r[0]; kfB[3] = r[1];
                r = __builtin_amdgcn_cvt_pk_f32_fp8(kdB.y, false); kfB[4] = r[0]; kfB[5] = r[1];
                r = __builtin_amdgcn_cvt_pk_f32_fp8(kdB.y, true);  kfB[6] = r[0]; kfB[7] = r[1];
                r = __builtin_amdgcn_cvt_pk_f32_fp8(kdB.z, false); kfB[8] = r[0]; kfB[9] = r[1];
                r = __builtin_amdgcn_cvt_pk_f32_fp8(kdB.z, true);  kfB[10] = r[0]; kfB[11] = r[1];
                r = __builtin_amdgcn_cvt_pk_f32_fp8(kdB.w, false); kfB[12] = r[0]; kfB[13] = r[1];
                r = __builtin_amdgcn_cvt_pk_f32_fp8(kdB.w, true);  kfB[14] = r[0]; kfB[15] = r[1];
            }
            float dot0 = 0.f, dot1 = 0.f;
#pragma unroll
            for (int j = 0; j < 16; j++) { dot0 += qf[j] * kfA[j]; dot1 += qf[j] * kfB[j]; }
            const float sc0 = act0 ? dot0 * 0.25f : -1e30f;
            const float sc1 = act1 ? dot1 * 0.25f : -1e30f;
            const float cm = fmaxf(sc0, sc1);
            if (e == 0) {
                m = cm;
            } else if (!__all(cm <= m + 8.f)) {
                const float nm = fmaxf(m, cm);
                const float s8 = __expf(m - nm);
                den *= s8;
#pragma unroll
                for (int i = 0; i < 16; i++) acc[i] *= s8;
                m = nm;
            }
            const float pp0 = act0 ? __expf(sc0 - m) : 0.f;
            const float pp1 = act1 ? __expf(sc1 - m) : 0.f;
            den += pp0 + pp1;
            {
                f32x2 r;
                r = __builtin_amdgcn_cvt_pk_f32_fp8(vdA.x, false); acc[0] += pp0 * r[0]; acc[1] += pp0 * r[1];
                r = __builtin_amdgcn_cvt_pk_f32_fp8(vdA.x, true);  acc[2] += pp0 * r[0]; acc[3] += pp0 * r[1];
                r = __builtin_amdgcn_cvt_pk_f32_fp8(vdA.y, false); acc[4] += pp0 * r[0]; acc[5] += pp0 * r[1];
                r = __builtin_amdgcn_cvt_pk_f32_fp8(vdA.y, true);  acc[6] += pp0 * r[0]; acc[7] += pp0 * r[1];
                r = __builtin_amdgcn_cvt_pk_f32_fp8(vdA.z, false); acc[8] += pp0 * r[0]; acc[9] += pp0 * r[1];
                r = __builtin_amdgcn_cvt_pk_f32_fp8(vdA.z, true);  acc[10] += pp0 * r[0]; acc[11] += pp0 * r[1];
                r = __builtin_amdgcn_cvt_pk_f32_fp8(vdA.w, false); acc[12] += pp0 * r[0]; acc[13] += pp0 * r[1];
                r = __builtin_amdgcn_cvt_pk_f32_fp8(vdA.w, true);  acc[14] += pp0 * r[0]; acc[15] += pp0 * r[1];
                r = __builtin_amdgcn_cvt_pk_f32_fp8(vdB.x, false); acc[0] += pp1 * r[0]; acc[1] += pp1 * r[1];
                r = __builtin_amdgcn_cvt_pk_f32_fp8(vdB.x, true);  acc[2] += pp1 * r[0]; acc[3] += pp1 * r[1];
                r = __builtin_amdgcn_cvt_pk_f32_fp8(vdB.y, false); acc[4] += pp1 * r[0]; acc[5] += pp1 * r[1];
                r = __builtin_amdgcn_cvt_pk_f32_fp8(vdB.y, true);  acc[6] += pp1 * r[0]; acc[7] += pp1 * r[1];
                r = __builtin_amdgcn_cvt_pk_f32_fp8(vdB.z, false); acc[8] += pp1 * r[0]; acc[9] += pp1 * r[1];
                r = __builtin_amdgcn_cvt_pk_f32_fp8(vdB.z, true);  acc[10] += pp1 * r[0]; acc[11] += pp1 * r[1];
                r = __builtin_amdgcn_cvt_pk_f32_fp8(vdB.w, false); acc[12] += pp1 * r[0]; acc[13] += pp1 * r[1];
                r = __builtin_amdgcn_cvt_pk_f32_fp8(vdB.w, true);  acc[14] += pp1 * r[0]; acc[15] += pp1 * r[1];
            }
            colC = ncolC; colD = ncolD;
            kdA = nkdA; vdA = nvdA; kdB = nkdB; vdB = nvdB;
        }
        const float inv = 1.f / (den + 1e-9f);
        u16x8 o0, o1;
#pragma unroll
        for (int j = 0; j < 8; j++) { o0[j] = f2bf(acc[j] * inv); o1[j] = f2bf(acc[8 + j] * inv); }
        const int base16 = rl * 128 + h * 16;
        *reinterpret_cast<u16x8*>(&aT[(base16) ^ ((rl & 7) << 3)]) = o0;
        *reinterpret_cast<u16x8*>(&aT[(base16 + 8) ^ ((rl & 7) << 3)]) = o1;
    }
    __syncthreads();  // aT(agg) + wbuf(wo h0) ready

    // P1a: agg @ wo, K-half 0 (kc 0..1)
    f32x4 acc[8];
#pragma unroll
    for (int g8 = 0; g8 < 8; g8++) acc[g8] = (f32x4){0.f, 0.f, 0.f, 0.f};
    {
        bf16x8 a0 = *reinterpret_cast<const bf16x8*>(&aT[(row * 128 + 0 * 32 + lg * 8) ^ ((row & 7) << 3)]);
        bf16x8 a1 = *reinterpret_cast<const bf16x8*>(&aT[(row * 128 + 1 * 32 + lg * 8) ^ ((row & 7) << 3)]);
#pragma unroll
        for (int g8 = 0; g8 < 8; g8++) {
            acc[g8] = __builtin_amdgcn_mfma_f32_16x16x32_bf16(
                a0, *reinterpret_cast<const bf16x8*>(&wbuf[((0 * 4 + lg) * 128 + g8 * 16 + lr) << 3]), acc[g8], 0, 0, 0);
            acc[g8] = __builtin_amdgcn_mfma_f32_16x16x32_bf16(
                a1, *reinterpret_cast<const bf16x8*>(&wbuf[((1 * 4 + lg) * 128 + g8 * 16 + lr) << 3]), acc[g8], 0, 0, 0);
        }
    }
    __syncthreads();
    // stage wo K-half 1
#pragma unroll
    for (int i = 0; i < 4; i++) {
        const int off = i * 2048 + t * 8;
        *reinterpret_cast<u16x8*>(&wbuf[off]) = *reinterpret_cast<const u16x8*>(wop + 8192 + off);
    }
    __syncthreads();

    // P1b: wo K-half 1 (kc 2..3) + residual + LN2
    {
        bf16x8 a2f = *reinterpret_cast<const bf16x8*>(&aT[(row * 128 + 2 * 32 + lg * 8) ^ ((row & 7) << 3)]);
        bf16x8 a3f = *reinterpret_cast<const bf16x8*>(&aT[(row * 128 + 3 * 32 + lg * 8) ^ ((row & 7) << 3)]);
#pragma unroll
        for (int g8 = 0; g8 < 8; g8++) {
            acc[g8] = __builtin_amdgcn_mfma_f32_16x16x32_bf16(
                a2f, *reinterpret_cast<const bf16x8*>(&wbuf[((0 * 4 + lg) * 128 + g8 * 16 + lr) << 3]), acc[g8], 0, 0, 0);
            acc[g8] = __builtin_amdgcn_mfma_f32_16x16x32_bf16(
                a3f, *reinterpret_cast<const bf16x8*>(&wbuf[((1 * 4 + lg) * 128 + g8 * 16 + lr) << 3]), acc[g8], 0, 0, 0);
        }
    }
    float hv[8][4];
#pragma unroll
    for (int g8 = 0; g8 < 8; g8++) {
        const float bias = bo[g8 * 16 + lr];
#pragma unroll
        for (int j = 0; j < 4; j++)
            hv[g8][j] = acc[g8][j] + bias + x[(size_t)(rb + m0 + 4 * lg + j) * HH + g8 * 16 + lr];
    }
    float mu[4], rs[4];
#pragma unroll
    for (int j = 0; j < 4; j++) {
        float s = 0.f, ss = 0.f;
#pragma unroll
        for (int g8 = 0; g8 < 8; g8++) { const float hh = hv[g8][j]; s += hh; ss += hh * hh; }
        s += __shfl_xor(s, 1); s += __shfl_xor(s, 2); s += __shfl_xor(s, 4); s += __shfl_xor(s, 8);
        ss += __shfl_xor(ss, 1); ss += __shfl_xor(ss, 2); ss += __shfl_xor(ss, 4); ss += __shfl_xor(ss, 8);
        mu[j] = s * (1.f / HH);
        rs[j] = rsqrtf(ss * (1.f / HH) - mu[j] * mu[j] + LNEPS);
    }
    __syncthreads();  // aT(agg) + wbuf(wo h1) reads complete

    // P2: hn -> aT ; stage w1 N-quarter 0
#pragma unroll
    for (int g8 = 0; g8 < 8; g8++) {
        const float gg = g2[g8 * 16 + lr], bb = bl2[g8 * 16 + lr];
#pragma unroll
        for (int j = 0; j < 4; j++) {
            const int i = m0 + 4 * lg + j;
            aT[(i * 128 + g8 * 16 + lr) ^ ((i & 7) << 3)] = f2bf((hv[g8][j] - mu[j]) * rs[j] * gg + bb);
        }
    }
#pragma unroll
    for (int i = 0; i < 4; i++) {
        const int gi = i * 256 + t;              // group index in [0,1024)
        const int k8 = gi >> 6, np = gi & 63;    // w1 quarter 0: n = np
        *reinterpret_cast<u16x8*>(&wbuf[gi * 8]) =
            *reinterpret_cast<const u16x8*>(w1p + ((size_t)(k8 * 256 + np) << 3));
    }
    __syncthreads();

    // hn fragments (aT stable from here)
    bf16x8 a2[4];
#pragma unroll
    for (int kc = 0; kc < 4; kc++)
        a2[kc] = *reinterpret_cast<const bf16x8*>(&aT[(row * 128 + kc * 32 + lg * 8) ^ ((row & 7) << 3)]);

    // ---- mlp1/mlp2 interleaved in 4 column-quarters ----
    f32x4 acc2[8];
#pragma unroll
    for (int g8 = 0; g8 < 8; g8++) acc2[g8] = (f32x4){0.f, 0.f, 0.f, 0.f};
#pragma unroll 1
    for (int c = 0; c < 4; c++) {
        // m1: hn @ w1 quarter c -> tT (4 G-tiles x 4 kc)
#pragma unroll 1
        for (int Gl = 0; Gl < 4; Gl++) {
            f32x4 a1 = (f32x4){0.f, 0.f, 0.f, 0.f};
#pragma unroll
            for (int kc = 0; kc < 4; kc++)
                a1 = __builtin_amdgcn_mfma_f32_16x16x32_bf16(
                    a2[kc],
                    *reinterpret_cast<const bf16x8*>(&wbuf[(((kc << 2) + lg) * 64 + Gl * 16 + lr) << 3]),
                    a1, 0, 0, 0);
            const float bias = b1[(c * 4 + Gl) * 16 + lr];
#pragma unroll
            for (int j = 0; j < 4; j++) {
                const int i = m0 + 4 * lg + j;
                tT[(i * 64 + Gl * 16 + lr) ^ ((i & 7) << 3)] = f2bf(gelu_tanh(a1[j] + bias));
            }
        }
        __syncthreads();  // wbuf(w1 qc) reads + tT writes done
        // stage w2 K-quarter c (contiguous 16 KB)
#pragma unroll
        for (int i = 0; i < 4; i++) {
            const int off = i * 2048 + t * 8;
            *reinterpret_cast<u16x8*>(&wbuf[off]) = *reinterpret_cast<const u16x8*>(w2p + c * 8192 + off);
        }
        __syncthreads();
        // m2: tT @ w2 quarter c -> acc2 (8 g8 x 2 kc)
        {
            bf16x8 b0 = *reinterpret_cast<const bf16x8*>(&tT[(row * 64 + 0 * 32 + lg * 8) ^ ((row & 7) << 3)]);
            bf16x8 b1f = *reinterpret_cast<const bf16x8*>(&tT[(row * 64 + 1 * 32 + lg * 8) ^ ((row & 7) << 3)]);
#pragma unroll
            for (int g8 = 0; g8 < 8; g8++) {
                acc2[g8] = __builtin_amdgcn_mfma_f32_16x16x32_bf16(
                    b0, *reinterpret_cast<const bf16x8*>(&wbuf[((0 * 4 + lg) * 128 + g8 * 16 + lr) << 3]), acc2[g8], 0, 0, 0);
                acc2[g8] = __builtin_amdgcn_mfma_f32_16x16x32_bf16(
                    b1f, *reinterpret_cast<const bf16x8*>(&wbuf[((1 * 4 + lg) * 128 + g8 * 16 + lr) << 3]), acc2[g8], 0, 0, 0);
            }
        }
        __syncthreads();  // wbuf(w2 qc) + tT reads done
        if (c < 3) {
            // stage w1 N-quarter c+1 (strided, coalesced)
#pragma unroll
            for (int i = 0; i < 4; i++) {
                const int gi = i * 256 + t;
                const int k8 = gi >> 6, np = gi & 63;
                *reinterpret_cast<u16x8*>(&wbuf[gi * 8]) =
                    *reinterpret_cast<const u16x8*>(w1p + ((size_t)(k8 * 256 + (c + 1) * 64 + np) << 3));
            }
            __syncthreads();
        }
    }
    // epilogue
#pragma unroll
    for (int g8 = 0; g8 < 8; g8++) {
        const float bias = b2[g8 * 16 + lr];
#pragma unroll
        for (int j = 0; j < 4; j++)
            out[(size_t)(rb + m0 + 4 * lg + j) * HH + g8 * 16 + lr] = hv[g8][j] + acc2[g8][j] + bias;
    }
}

extern "C" void kernel_launch(void* const* d_in, const int* in_sizes, int n_in,
                              void* d_out, int out_size, void* d_ws, size_t ws_size,
                              hipStream_t stream) {
    const float* x = (const float*)d_in[0];
    const int* erow = (const int*)d_in[1];
    const int* ecol = (const int*)d_in[2];
    const float* ln1g = (const float*)d_in[3];
    const float* ln1b = (const float*)d_in[4];
    const float* wq = (const float*)d_in[5];
    const float* bq = (const float*)d_in[6];
    const float* wk = (const float*)d_in[7];
    const float* bk = (const float*)d_in[8];
    const float* wv = (const float*)d_in[9];
    const float* bv = (const float*)d_in[10];
    const float* wo = (const float*)d_in[11];
    const float* bo = (const float*)d_in[12];
    const float* ln2g = (const float*)d_in[13];
    const float* ln2b = (const float*)d_in[14];
    const float* w1 = (const float*)d_in[15];
    const float* b1 = (const float*)d_in[16];
    const float* w2 = (const float*)d_in[17];
    const float* b2 = (const float*)d_in[18];
    float* out = (float*)d_out;

    unsigned short* qb = (unsigned short*)d_ws;                        // NN*128 ushort (16 MB)
    unsigned char* kv8 = (unsigned char*)(qb + (size_t)NN * HH);       // NN*256 bytes (16 MB)
    unsigned short* wpack = (unsigned short*)(kv8 + (size_t)NN * 256); // 81920 ushorts (wo|w1|w2)
    int* offs = (int*)(wpack + 81920);                                 // NN+1 ints
    int* csr_col = offs + NN + 1;                                      // NE ints (4 MB)
    int* gcur = csr_col + NE;                                          // NB ints
    unsigned long long* pairs = (unsigned long long*)(gcur + NB + 2);  // NB*BCAP (12 MB)

    hipMemsetAsync(gcur, 0, NB * sizeof(int), stream);
    k_qkv_bin<<<768, 256, 0, stream>>>(x, ln1g, ln1b, wq, wk, wv, bq, bk, bv,
                                       qb, kv8, erow, ecol, gcur, pairs);
    k_csr_pack<<<576, 256, 0, stream>>>(pairs, gcur, offs, csr_col,
                                        wo, w1, w2, wpack);
    k_at<<<NN / 64, 256, 0, stream>>>(qb, kv8, offs, csr_col,
                                      wpack, bo, x, ln2g, ln2b,
                                      wpack + 16384, b1, wpack + 49152, b2, out);
}